// Round 3
// baseline (169.803 us; speedup 1.0000x reference)
//
#include <hip/hip_runtime.h>
#include <hip/hip_bf16.h>

// SDF volume rendering (NeuS/VolSDF-style), float32 in/out.
//
// Per ray (96 samples):
//   alpha_i = 1 - exp(-beta * sigmoid(-sdf_i * beta))
//   t_i     = 1 - alpha_i + 1e-10 = exp(-beta * sigmoid(-sdf_i*beta)) + 1e-10
//   trans_i = prod_{j<i} t_j          (exclusive cumprod)
//   w_i     = alpha_i * trans_i
//   depth   = sum w_i * z_i ;  rgb_c = sum w_i * rgb_{i,c}
//
// R3 layout: 32 lanes per ray, lane l owns samples [3l, 3l+3) (contiguous).
// All 96 samples processed in ONE round:
//   m_l = t_{3l} t_{3l+1} t_{3l+2}          (2 local mults)
//   E_l = exclusive 32-lane prefix product of m   (5-step shuffle scan + 1)
//   w_{3l+j} = alpha_{3l+j} * E_l * (local exclusive products)
// This cuts cross-lane shuffles 41 -> 26 and removes the serial cross-round
// carry that made R2 latency-bound (VALUBusy 17%, HBM 25%, nothing saturated).
// Per-lane loads are 12B/12B/36B contiguous -> wide coalesced VMEM, good MLP.
// sdf/z passthrough outputs stored from already-loaded values (bit-exact).

#define SDFR_N_SAMPLES 96

__global__ __launch_bounds__(256) void sdf_render_kernel(
    const float*  __restrict__ rgb,     // [N, 96, 3] f32
    const float*  __restrict__ sdf,     // [N, 96]    f32
    const float*  __restrict__ zv,      // [N, 96]    f32
    const int*    __restrict__ beta_p,  // scalar (int32, or f32 bit pattern)
    float* __restrict__ out_depth,      // [N]
    float* __restrict__ out_rgb,        // [N, 3]
    float* __restrict__ out_sdf,        // [N, 96]
    float* __restrict__ out_z,          // [N, 96]
    int n_rays)
{
    // Defensive beta decode: small int is the value; huge magnitude is an
    // f32 bit pattern (10.0f = 0x41200000).
    int bi = *beta_p;
    float beta;
    if (bi > 1000000 || bi < -1000000) {
        union { int i; float f; } c; c.i = bi; beta = c.f;
    } else {
        beta = (float)bi;
    }

    const int lane = threadIdx.x & 63;
    const int half = lane >> 5;        // which ray within the wave
    const int l    = lane & 31;        // lane within the 32-lane ray group
    const int wave = threadIdx.x >> 6; // wave within block (0..3)
    const int ray  = (blockIdx.x * 4 + wave) * 2 + half;
    if (ray >= n_rays) return;

    const int base = ray * SDFR_N_SAMPLES + 3 * l;  // this lane's 3 samples

    // ---- wide independent loads, issued before any math ----
    const float s0 = sdf[base + 0];
    const float s1 = sdf[base + 1];
    const float s2 = sdf[base + 2];
    const float z0 = zv[base + 0];
    const float z1 = zv[base + 1];
    const float z2 = zv[base + 2];
    const float* rp = rgb + (size_t)base * 3;
    float c[9];
    #pragma unroll
    for (int i = 0; i < 9; ++i) c[i] = rp[i];

    // ---- passthrough stores (bit-exact) ----
    out_sdf[base + 0] = s0;
    out_sdf[base + 1] = s1;
    out_sdf[base + 2] = s2;
    out_z[base + 0]   = z0;
    out_z[base + 1]   = z1;
    out_z[base + 2]   = z2;

    // ---- per-sample alpha / t ----
    // sigmoid(-s*beta) = 1/(1+exp(s*beta)); e = exp(-beta*sig)
    const float e0 = __expf(-beta * __builtin_amdgcn_rcpf(1.0f + __expf(s0 * beta)));
    const float e1 = __expf(-beta * __builtin_amdgcn_rcpf(1.0f + __expf(s1 * beta)));
    const float e2 = __expf(-beta * __builtin_amdgcn_rcpf(1.0f + __expf(s2 * beta)));
    const float a0 = 1.0f - e0, t0 = e0 + 1e-10f;
    const float a1 = 1.0f - e1, t1 = e1 + 1e-10f;
    const float a2 = 1.0f - e2, t2 = e2 + 1e-10f;

    // ---- 32-lane exclusive prefix product of per-lane local product ----
    const float m = t0 * t1 * t2;
    float scan = m;
    #pragma unroll
    for (int d = 1; d < 32; d <<= 1) {
        float v = __shfl_up(scan, d, 32);
        if (l >= d) scan *= v;
    }
    float E = __shfl_up(scan, 1, 32);   // inclusive at l-1
    if (l == 0) E = 1.0f;               // exclusive prefix for lane 0

    // ---- weights for this lane's 3 samples ----
    const float w0 = a0 * E;
    const float w1 = a1 * E * t0;
    const float w2 = a2 * E * t0 * t1;

    // ---- per-lane partial sums ----
    float depth = w0 * z0 + w1 * z1 + w2 * z2;
    float r0 = w0 * c[0] + w1 * c[3] + w2 * c[6];
    float r1 = w0 * c[1] + w1 * c[4] + w2 * c[7];
    float r2 = w0 * c[2] + w1 * c[5] + w2 * c[8];

    // ---- butterfly reduction across the 32-lane segment ----
    #pragma unroll
    for (int d = 16; d >= 1; d >>= 1) {
        depth += __shfl_xor(depth, d, 32);
        r0    += __shfl_xor(r0, d, 32);
        r1    += __shfl_xor(r1, d, 32);
        r2    += __shfl_xor(r2, d, 32);
    }

    if (l == 0) {
        out_depth[ray]       = depth;
        out_rgb[ray * 3 + 0] = r0;
        out_rgb[ray * 3 + 1] = r1;
        out_rgb[ray * 3 + 2] = r2;
    }
}

extern "C" void kernel_launch(void* const* d_in, const int* in_sizes, int n_in,
                              void* d_out, int out_size, void* d_ws, size_t ws_size,
                              hipStream_t stream) {
    (void)n_in; (void)d_ws; (void)ws_size; (void)out_size;

    const float* rgb    = (const float*)d_in[0];
    const float* sdf    = (const float*)d_in[1];
    const float* zv     = (const float*)d_in[2];
    const int*   beta_p = (const int*)d_in[3];

    const int n_rays = in_sizes[1] / SDFR_N_SAMPLES;  // 65536

    // output layout (f32 elements): depth[N] | rgb[N*3] | sdf[N*96] | z[N*96]
    float* out_depth = (float*)d_out;
    float* out_rgb   = out_depth + n_rays;
    float* out_sdf   = out_rgb   + (size_t)n_rays * 3;
    float* out_z     = out_sdf   + (size_t)n_rays * SDFR_N_SAMPLES;

    // 2 rays per wave64, 4 waves per block -> 8 rays/block
    const int rays_per_block = 8;
    const int grid = (n_rays + rays_per_block - 1) / rays_per_block;
    sdf_render_kernel<<<grid, 256, 0, stream>>>(
        rgb, sdf, zv, beta_p, out_depth, out_rgb, out_sdf, out_z, n_rays);
}

// Round 4
// 169.641 us; speedup vs baseline: 1.0010x; 1.0010x over previous
//
#include <hip/hip_runtime.h>
#include <hip/hip_bf16.h>

// SDF volume rendering (NeuS/VolSDF-style), float32 in/out.
//
// Per ray (96 samples):
//   alpha_i = 1 - exp(-beta * sigmoid(-sdf_i * beta))
//   t_i     = 1 - alpha_i + 1e-10 = exp(-beta * sigmoid(-sdf_i*beta)) + 1e-10
//   trans_i = exclusive cumprod of t ;  w_i = alpha_i * trans_i
//   depth   = sum w_i * z_i ;  rgb_c = sum w_i * rgb_{i,c}
//
// R4: R2/R3 were latency-bound (VGPR_Count=20 -> compiler serialized the
// per-lane loads; both kernels pinned at 57us with VALUBusy ~13%, HBM 25%).
// Fix: stage through LDS with 5 independent float4 global loads per thread
// (sdf+z combined: 2, rgb: 3), held live for LDS + passthrough stores so the
// compiler cannot serialize them. Passthrough stores are float4 streams
// (the 6.29 TB/s copy ubench pattern). Compute phase (scan/reduce) reads
// from LDS: stride-3 / stride-9 dword reads -> odd stride, conflict-free
// (the 2-way wave64 aliasing is free on gfx950, m136).
//
// Block = 256 threads = 8 rays (32 lanes/ray). LDS 15360B * 8 blocks/CU
// = 120KB < 160KB; __launch_bounds__(256,8) caps VGPR at 64 for full
// 32-wave/CU occupancy.

#define SDFR_NS 96
#define SDFR_RPB 8   // rays per block

__global__ __launch_bounds__(256, 8) void sdf_render_kernel(
    const float4* __restrict__ rgb4,    // [N*96*3/4] f32x4
    const float4* __restrict__ sdf4,    // [N*96/4]
    const float4* __restrict__ z4,      // [N*96/4]
    const int*    __restrict__ beta_p,  // scalar (int32, or f32 bit pattern)
    float*  __restrict__ out_depth,     // [N]
    float*  __restrict__ out_rgb,       // [N,3]
    float4* __restrict__ out_sdf4,      // [N*96/4]
    float4* __restrict__ out_z4,        // [N*96/4]
    int n_rays)
{
    __shared__ float4 sz_s[384];    // [0,192) = sdf, [192,384) = z   (f4 units)
    __shared__ float4 rgb_s[576];   // 8 rays * 288 floats / 4

    const int t  = threadIdx.x;
    const int r0 = blockIdx.x * SDFR_RPB;

    const long base4  = (long)r0 * (SDFR_NS / 4);      // r0*24  (sdf/z f4 idx)
    const long rbase4 = (long)r0 * (SDFR_NS * 3 / 4);  // r0*72  (rgb f4 idx)

    // ---- staging indices: 384 f4 of sdf+z, 576 f4 of rgb, 256 threads ----
    const int f1 = t;
    const int f2 = (256 + t > 383) ? 383 : 256 + t;    // clamped dup = benign
    const int g1 = t;
    const int g2 = 256 + t;
    const int g3 = (512 + t > 575) ? 575 : 512 + t;    // clamped dup = benign

    const float4* p1 = (f1 < 192) ? (sdf4 + base4 + f1)
                                  : (z4   + base4 + (f1 - 192));
    const float4* p2 = (f2 < 192) ? (sdf4 + base4 + f2)
                                  : (z4   + base4 + (f2 - 192));

    // ---- 5 independent wide loads, all in flight together ----
    const float4 va  = *p1;
    const float4 vb  = *p2;
    const float4 vc1 = rgb4[rbase4 + g1];
    const float4 vc2 = rgb4[rbase4 + g2];
    const float4 vc3 = rgb4[rbase4 + g3];

    // beta decode: small int is the value; huge magnitude is an f32 pattern
    int bi = *beta_p;
    float beta;
    if (bi > 1000000 || bi < -1000000) {
        union { int i; float f; } u; u.i = bi; beta = u.f;
    } else {
        beta = (float)bi;
    }

    // ---- passthrough global stores (bit-exact float4 streams) ----
    float4* q1 = (f1 < 192) ? (out_sdf4 + base4 + f1)
                            : (out_z4   + base4 + (f1 - 192));
    float4* q2 = (f2 < 192) ? (out_sdf4 + base4 + f2)
                            : (out_z4   + base4 + (f2 - 192));
    *q1 = va;
    *q2 = vb;

    // ---- LDS stage ----
    sz_s[f1]  = va;
    sz_s[f2]  = vb;
    rgb_s[g1] = vc1;
    rgb_s[g2] = vc2;
    rgb_s[g3] = vc3;

    __syncthreads();

    // ---- compute phase: 32 lanes per ray, lane l owns samples [3l,3l+3) ----
    const int g   = t >> 5;        // ray group within block
    const int l   = t & 31;
    const int ray = r0 + g;

    const float* szf  = (const float*)sz_s;   // sdf: [0,768), z: [768,1536)
    const float* rgbf = (const float*)rgb_s;

    const int sb = g * SDFR_NS + 3 * l;
    const float s0 = szf[sb], s1 = szf[sb + 1], s2 = szf[sb + 2];
    const float z0 = szf[768 + sb], z1 = szf[768 + sb + 1], z2 = szf[768 + sb + 2];

    const int rb = g * (SDFR_NS * 3) + 9 * l;
    const float c0 = rgbf[rb + 0], c1 = rgbf[rb + 1], c2 = rgbf[rb + 2];
    const float c3 = rgbf[rb + 3], c4 = rgbf[rb + 4], c5 = rgbf[rb + 5];
    const float c6 = rgbf[rb + 6], c7 = rgbf[rb + 7], c8 = rgbf[rb + 8];

    // sigmoid(-s*beta) = 1/(1+exp(s*beta)); e = exp(-beta*sig)
    const float e0 = __expf(-beta * __builtin_amdgcn_rcpf(1.0f + __expf(s0 * beta)));
    const float e1 = __expf(-beta * __builtin_amdgcn_rcpf(1.0f + __expf(s1 * beta)));
    const float e2 = __expf(-beta * __builtin_amdgcn_rcpf(1.0f + __expf(s2 * beta)));
    const float a0 = 1.0f - e0, t0 = e0 + 1e-10f;
    const float a1 = 1.0f - e1, t1 = e1 + 1e-10f;
    const float a2 = 1.0f - e2, t2 = e2 + 1e-10f;

    // 32-lane exclusive prefix product of per-lane local product
    const float m = t0 * t1 * t2;
    float scan = m;
    #pragma unroll
    for (int d = 1; d < 32; d <<= 1) {
        float v = __shfl_up(scan, d, 32);
        if (l >= d) scan *= v;
    }
    float E = __shfl_up(scan, 1, 32);
    if (l == 0) E = 1.0f;

    const float w0 = a0 * E;
    const float w1 = a1 * E * t0;
    const float w2 = a2 * E * t0 * t1;

    float depth = w0 * z0 + w1 * z1 + w2 * z2;
    float r0acc = w0 * c0 + w1 * c3 + w2 * c6;
    float r1acc = w0 * c1 + w1 * c4 + w2 * c7;
    float r2acc = w0 * c2 + w1 * c5 + w2 * c8;

    #pragma unroll
    for (int d = 16; d >= 1; d >>= 1) {
        depth += __shfl_xor(depth, d, 32);
        r0acc += __shfl_xor(r0acc, d, 32);
        r1acc += __shfl_xor(r1acc, d, 32);
        r2acc += __shfl_xor(r2acc, d, 32);
    }

    if (l == 0 && ray < n_rays) {
        out_depth[ray]       = depth;
        out_rgb[ray * 3 + 0] = r0acc;
        out_rgb[ray * 3 + 1] = r1acc;
        out_rgb[ray * 3 + 2] = r2acc;
    }
}

extern "C" void kernel_launch(void* const* d_in, const int* in_sizes, int n_in,
                              void* d_out, int out_size, void* d_ws, size_t ws_size,
                              hipStream_t stream) {
    (void)n_in; (void)d_ws; (void)ws_size; (void)out_size;

    const float4* rgb4   = (const float4*)d_in[0];
    const float4* sdf4   = (const float4*)d_in[1];
    const float4* z4     = (const float4*)d_in[2];
    const int*    beta_p = (const int*)d_in[3];

    const int n_rays = in_sizes[1] / SDFR_NS;  // 65536

    // output layout (f32): depth[N] | rgb[N*3] | sdf[N*96] | z[N*96]
    float* out_depth = (float*)d_out;
    float* out_rgb   = out_depth + n_rays;
    float* out_sdf   = out_rgb   + (size_t)n_rays * 3;
    float* out_z     = out_sdf   + (size_t)n_rays * SDFR_NS;

    const int grid = (n_rays + SDFR_RPB - 1) / SDFR_RPB;  // 8192
    sdf_render_kernel<<<grid, 256, 0, stream>>>(
        rgb4, sdf4, z4, beta_p, out_depth, out_rgb,
        (float4*)out_sdf, (float4*)out_z, n_rays);
}